// Round 5
// baseline (73.305 us; speedup 1.0000x reference)
//
#include <hip/hip_runtime.h>

// Single-wave workgroup per ray: 2048 blocks x 64 threads. For one-wave
// groups the compiler elides s_barrier (__syncthreads -> s_waitcnt only),
// the LDS compact atomic serializes only within one wave (m ~ 10), and all
// resident waves do useful work (no wave-0-only phase with 3 idle waves).
// Phase 1: 16 voxels/lane, all 16 float4 position/size loads issued up
// front (one latency exposure, deep ILP). Payload (ws, depth, SH rgb)
// computed only on hit; compacted to LDS.
// Phase 2: sort-free composite — T_before(l) = prod over {j: key_j < key_l}
// of (1 - ws_j); proc = (T_before >= 0.01); bg=0 so T_final never needed.
// Butterfly reduce, write.

#define BLOCK 64
#define VPT   16         // voxels per lane (N = 1024)
#define CAP   128
#define EARLY_STOP 0.01f

__global__ __launch_bounds__(BLOCK) void voxel_raster(
    const float* __restrict__ positions, const float* __restrict__ sizes,
    const float* __restrict__ densities, const float* __restrict__ colors,
    const float* __restrict__ ray_o, const float* __restrict__ ray_d,
    float* __restrict__ out, int B)
{
    const int b   = blockIdx.x;
    const int tid = threadIdx.x;

    __shared__ int cnt;
    __shared__ unsigned long long key[CAP];
    __shared__ float h_ws[CAP], h_dep[CAP], h_r[CAP], h_g[CAP], h_b[CAP];

    if (tid == 0) cnt = 0;
    __syncthreads();   // single wave: lowers to waitcnt, no s_barrier

    const float ox = ray_o[b*3+0], oy = ray_o[b*3+1], oz = ray_o[b*3+2];
    const float dx = ray_d[b*3+0], dy = ray_d[b*3+1], dz = ray_d[b*3+2];
    const float ivx = 1.0f/dx, ivy = 1.0f/dy, ivz = 1.0f/dz;

    // degree-2 real SH basis at ray direction (wave-uniform)
    float sh[9];
    sh[0]=1.0f; sh[1]=dy; sh[2]=dz; sh[3]=dx;
    sh[4]=dx*dy; sh[5]=dy*dz; sh[6]=3.0f*dz*dz-1.0f; sh[7]=dx*dz; sh[8]=dx*dx-dy*dy;

    // ---- phase 1: 16 consecutive voxels per lane, loads issued up front ----
    float4 P[12], SZ[4];
    #pragma unroll
    for (int i = 0; i < 12; ++i) P[i]  = ((const float4*)positions)[tid*12 + i];
    #pragma unroll
    for (int i = 0; i < 4;  ++i) SZ[i] = ((const float4*)sizes)[tid*4 + i];
    const float* pf = (const float*)P;   // 48 contiguous floats (16 voxels x 3)
    const float* sf = (const float*)SZ;  // 16 sizes

    #pragma unroll
    for (int k = 0; k < VPT; ++k) {
        const int n = tid*VPT + k;
        const float half = sf[k] * 0.5f;
        const float px = pf[k*3+0], py = pf[k*3+1], pz = pf[k*3+2];

        float a0 = (px - half - ox) * ivx, a1 = (px + half - ox) * ivx;
        float tn = fminf(a0, a1), tf = fmaxf(a0, a1);
        a0 = (py - half - oy) * ivy; a1 = (py + half - oy) * ivy;
        tn = fmaxf(tn, fminf(a0, a1)); tf = fminf(tf, fmaxf(a0, a1));
        a0 = (pz - half - oz) * ivz; a1 = (pz + half - oz) * ivz;
        tn = fmaxf(tn, fminf(a0, a1)); tf = fminf(tf, fmaxf(a0, a1));

        if ((tf > tn) && (tf > 0.0f)) {
            // within-voxel alpha compositing (S=8, constant sigma)
            const float sigma = __expf(densities[n]);
            const float dt    = tf - tn;
            const float alpha = 1.0f - __expf(-sigma * dt * 0.125f);
            const float base  = 1.0f - alpha + 1e-8f;
            float pw = 1.0f, ws = 0.0f, dep = 0.0f;
            #pragma unroll
            for (int i = 0; i < 8; i++) {
                const float w  = alpha * pw;
                const float ts = tn + dt * ((float)i * (1.0f / 7.0f));
                ws  += w;
                dep += w * ts;
                pw  *= base;
            }
            // SH color + sigmoid
            float rgb[3];
            #pragma unroll
            for (int c3 = 0; c3 < 3; c3++) {
                float acc = 0.0f;
                #pragma unroll
                for (int c = 0; c < 9; c++)
                    acc += sh[c] * colors[n*27 + c3*9 + c];
                rgb[c3] = __fdividef(1.0f, 1.0f + __expf(-acc));
            }

            const int slot = atomicAdd(&cnt, 1);
            if (slot < CAP) {
                unsigned u = __float_as_uint(tn);
                u = (u & 0x80000000u) ? ~u : (u | 0x80000000u);
                key[slot]   = ((unsigned long long)u << 32) | (unsigned)n;
                h_ws[slot]  = ws;
                h_dep[slot] = dep;
                h_r[slot]   = rgb[0];
                h_g[slot]   = rgb[1];
                h_b[slot]   = rgb[2];
            }
        }
    }
    __syncthreads();   // waitcnt only (single wave)

    const int total = cnt;
    const int m = (total < CAP) ? total : CAP;

    // ---- phase 2: sort-free predicate-product composite (all 64 lanes) ----
    float ra = 0.f, ga = 0.f, ba = 0.f, da = 0.f, wa = 0.f;
    for (int l = tid; l < m; l += BLOCK) {
        const unsigned long long kl = key[l];
        float Tb = 1.0f;
        for (int j = 0; j < m; ++j) {            // broadcast LDS reads
            const unsigned long long kj = key[j];
            const float wj = h_ws[j];
            Tb *= (kj < kl) ? (1.0f - wj) : 1.0f;
        }
        if (Tb >= EARLY_STOP) {                  // proc mask
            const float ws = h_ws[l];
            const float c  = Tb * ws;
            ra += c * h_r[l];
            ga += c * h_g[l];
            ba += c * h_b[l];
            da += Tb * h_dep[l];
            wa += c;
        }
    }
    // butterfly reduce the 5 sums across the wave
    #pragma unroll
    for (int off = 32; off > 0; off >>= 1) {
        ra += __shfl_down(ra, off, 64);
        ga += __shfl_down(ga, off, 64);
        ba += __shfl_down(ba, off, 64);
        da += __shfl_down(da, off, 64);
        wa += __shfl_down(wa, off, 64);
    }
    if (tid == 0) {
        out[b*3+0] = ra;
        out[b*3+1] = ga;
        out[b*3+2] = ba;
        out[B*3+b] = (total > 0) ? da : 100.0f;   // FAR_PLANE if no hit
        out[B*4+b] = wa;
    }
}

extern "C" void kernel_launch(void* const* d_in, const int* in_sizes, int n_in,
                              void* d_out, int out_size, void* d_ws, size_t ws_size,
                              hipStream_t stream) {
    const float* positions = (const float*)d_in[0];
    const float* sizes     = (const float*)d_in[1];
    const float* densities = (const float*)d_in[2];
    const float* colors    = (const float*)d_in[3];
    const float* ray_o     = (const float*)d_in[4];
    const float* ray_d     = (const float*)d_in[5];
    const int B = in_sizes[4] / 3;      // 2048 rays (N fixed at 1024)

    voxel_raster<<<B, BLOCK, 0, stream>>>(
        positions, sizes, densities, colors, ray_o, ray_d, (float*)d_out, B);
}

// Round 6
// 71.216 us; speedup vs baseline: 1.0293x; 1.0293x over previous
//
#include <hip/hip_runtime.h>

// R4 structure (best measured: 70.65 us): block-per-ray, 256 threads,
// 4 consecutive voxels/thread, sort-free predicate-product composite.
// Change vs R4: ballot-based compaction — per wave one __ballot + mbcnt
// prefix gives each hit lane its slot; a single atomicAdd per wave (not
// per hit) reserves the range. Removes ~10 serialized LDS-atomic
// round-trips per block.

#define BLOCK 256
#define CAP   128
#define EARLY_STOP 0.01f

__global__ __launch_bounds__(BLOCK) void voxel_raster(
    const float* __restrict__ positions, const float* __restrict__ sizes,
    const float* __restrict__ densities, const float* __restrict__ colors,
    const float* __restrict__ ray_o, const float* __restrict__ ray_d,
    float* __restrict__ out, int B)
{
    const int b    = blockIdx.x;
    const int tid  = threadIdx.x;
    const int lane = tid & 63;

    __shared__ int cnt;
    __shared__ unsigned long long key[CAP];
    __shared__ float h_ws[CAP], h_dep[CAP], h_r[CAP], h_g[CAP], h_b[CAP];

    if (tid == 0) cnt = 0;
    __syncthreads();

    const float ox = ray_o[b*3+0], oy = ray_o[b*3+1], oz = ray_o[b*3+2];
    const float dx = ray_d[b*3+0], dy = ray_d[b*3+1], dz = ray_d[b*3+2];
    const float ivx = 1.0f/dx, ivy = 1.0f/dy, ivz = 1.0f/dz;

    // degree-2 real SH basis at ray direction (block-uniform)
    float sh[9];
    sh[0]=1.0f; sh[1]=dy; sh[2]=dz; sh[3]=dx;
    sh[4]=dx*dy; sh[5]=dy*dz; sh[6]=3.0f*dz*dz-1.0f; sh[7]=dx*dz; sh[8]=dx*dx-dy*dy;

    // ---- phase 1: 4 consecutive voxels per thread, vectorized loads ----
    const float4 P0 = ((const float4*)positions)[tid*3+0];
    const float4 P1 = ((const float4*)positions)[tid*3+1];
    const float4 P2 = ((const float4*)positions)[tid*3+2];
    const float4 SZ = ((const float4*)sizes)[tid];

    const float pxa[4] = {P0.x, P0.w, P1.z, P2.y};
    const float pya[4] = {P0.y, P1.x, P1.w, P2.z};
    const float pza[4] = {P0.z, P1.y, P2.x, P2.w};
    const float hsa[4] = {SZ.x*0.5f, SZ.y*0.5f, SZ.z*0.5f, SZ.w*0.5f};

    #pragma unroll
    for (int k = 0; k < 4; ++k) {
        const int n = tid*4 + k;
        const float half = hsa[k];
        const float px = pxa[k], py = pya[k], pz = pza[k];

        float a0 = (px - half - ox) * ivx, a1 = (px + half - ox) * ivx;
        float tn = fminf(a0, a1), tf = fmaxf(a0, a1);
        a0 = (py - half - oy) * ivy; a1 = (py + half - oy) * ivy;
        tn = fmaxf(tn, fminf(a0, a1)); tf = fminf(tf, fmaxf(a0, a1));
        a0 = (pz - half - oz) * ivz; a1 = (pz + half - oz) * ivz;
        tn = fmaxf(tn, fminf(a0, a1)); tf = fminf(tf, fmaxf(a0, a1));

        const bool hit = (tf > tn) && (tf > 0.0f);

        // ballot-based compaction: one atomic per wave, prefix via mbcnt
        const unsigned long long mask = __ballot(hit);
        int slot = -1;
        if (mask) {
            const int nhits = __popcll(mask);
            int base;
            if (lane == __ffsll((long long)mask) - 1)
                base = atomicAdd(&cnt, nhits);
            base = __shfl(base, __ffsll((long long)mask) - 1, 64);
            if (hit) {
                const int pre = __popcll(mask & ((1ull << lane) - 1ull));
                slot = base + pre;
            }
        }

        if (hit && slot < CAP) {
            // within-voxel alpha compositing (S=8, constant sigma)
            const float sigma = __expf(densities[n]);
            const float dt    = tf - tn;
            const float alpha = 1.0f - __expf(-sigma * dt * 0.125f);
            const float base_ = 1.0f - alpha + 1e-8f;
            float pw = 1.0f, ws = 0.0f, dep = 0.0f;
            #pragma unroll
            for (int i = 0; i < 8; i++) {
                const float w  = alpha * pw;
                const float ts = tn + dt * ((float)i * (1.0f / 7.0f));
                ws  += w;
                dep += w * ts;
                pw  *= base_;
            }
            // SH color + sigmoid
            float rgb[3];
            #pragma unroll
            for (int c3 = 0; c3 < 3; c3++) {
                float acc = 0.0f;
                #pragma unroll
                for (int c = 0; c < 9; c++)
                    acc += sh[c] * colors[n*27 + c3*9 + c];
                rgb[c3] = __fdividef(1.0f, 1.0f + __expf(-acc));
            }

            unsigned u = __float_as_uint(tn);
            u = (u & 0x80000000u) ? ~u : (u | 0x80000000u);
            key[slot]   = ((unsigned long long)u << 32) | (unsigned)n;
            h_ws[slot]  = ws;
            h_dep[slot] = dep;
            h_r[slot]   = rgb[0];
            h_g[slot]   = rgb[1];
            h_b[slot]   = rgb[2];
        }
    }
    __syncthreads();

    const int total = cnt;
    const int m = (total < CAP) ? total : CAP;

    // ---- phase 2 (wave 0): sort-free predicate-product composite ----
    if (tid < 64) {
        float ra = 0.f, ga = 0.f, ba = 0.f, da = 0.f, wa = 0.f;
        for (int l = tid; l < m; l += 64) {
            const unsigned long long kl = key[l];
            float Tb = 1.0f;
            for (int j = 0; j < m; ++j) {            // broadcast LDS reads
                const unsigned long long kj = key[j];
                const float wj = h_ws[j];
                Tb *= (kj < kl) ? (1.0f - wj) : 1.0f;
            }
            if (Tb >= EARLY_STOP) {                  // proc mask
                const float ws = h_ws[l];
                const float c  = Tb * ws;
                ra += c * h_r[l];
                ga += c * h_g[l];
                ba += c * h_b[l];
                da += Tb * h_dep[l];
                wa += c;
            }
        }
        #pragma unroll
        for (int off = 32; off > 0; off >>= 1) {
            ra += __shfl_down(ra, off, 64);
            ga += __shfl_down(ga, off, 64);
            ba += __shfl_down(ba, off, 64);
            da += __shfl_down(da, off, 64);
            wa += __shfl_down(wa, off, 64);
        }
        if (tid == 0) {
            out[b*3+0] = ra;
            out[b*3+1] = ga;
            out[b*3+2] = ba;
            out[B*3+b] = (total > 0) ? da : 100.0f;   // FAR_PLANE if no hit
            out[B*4+b] = wa;
        }
    }
}

extern "C" void kernel_launch(void* const* d_in, const int* in_sizes, int n_in,
                              void* d_out, int out_size, void* d_ws, size_t ws_size,
                              hipStream_t stream) {
    const float* positions = (const float*)d_in[0];
    const float* sizes     = (const float*)d_in[1];
    const float* densities = (const float*)d_in[2];
    const float* colors    = (const float*)d_in[3];
    const float* ray_o     = (const float*)d_in[4];
    const float* ray_d     = (const float*)d_in[5];
    const int B = in_sizes[4] / 3;      // 2048 rays (N fixed at 1024)

    voxel_raster<<<B, BLOCK, 0, stream>>>(
        positions, sizes, densities, colors, ray_o, ray_d, (float*)d_out, B);
}